// Round 1
// baseline (2823.372 us; speedup 1.0000x reference)
//
#include <hip/hip_runtime.h>
#include <hip/hip_bf16.h>
#include <math.h>

#define BB 64
#define TT 256
#define CC 256
#define VV 65
#define LL 6
#define HH 8
#define HSZ 32
#define BT (BB*TT)   // 16384

// ---------------- pack per-head qkv weights into [L][C][768] ----------------
__global__ __launch_bounds__(256)
void pack_qkv_kernel(const float* __restrict__ wq, const float* __restrict__ wk,
                     const float* __restrict__ wv, const float* __restrict__ bq,
                     const float* __restrict__ bk, const float* __restrict__ bv,
                     float* __restrict__ Wp, float* __restrict__ Bp) {
    int e = blockIdx.x * blockDim.x + threadIdx.x;
    const int totalW = LL * CC * 768;
    if (e < totalW) {
        int l = e / (CC * 768);
        int r = e % (CC * 768);
        int c = r / 768;
        int j = r % 768;
        int which = j >> 8;          // 0=q 1=k 2=v
        int hd = j & 255;
        int h = hd >> 5, d = hd & 31;
        const float* src = (which == 0) ? wq : (which == 1) ? wk : wv;
        Wp[e] = src[(((size_t)l * HH + h) * CC + c) * HSZ + d];
    } else {
        int e2 = e - totalW;
        if (e2 < LL * 768) {
            int l = e2 / 768;
            int j = e2 % 768;
            int which = j >> 8;
            int hd = j & 255;
            int h = hd >> 5, d = hd & 31;
            const float* src = (which == 0) ? bq : (which == 1) ? bk : bv;
            Bp[e2] = src[((size_t)l * HH + h) * HSZ + d];
        }
    }
}

// ---------------- embedding: x = tok_emb[idx] + pos_emb ----------------
__global__ __launch_bounds__(256)
void embed_kernel(const int* __restrict__ idx, const float* __restrict__ te,
                  const float* __restrict__ pe, float* __restrict__ x) {
    int i = blockIdx.x * blockDim.x + threadIdx.x;   // over BT*64 float4s
    if (i >= BT * 64) return;
    int bt = i >> 6, c4 = i & 63;
    int tok = idx[bt];
    int t = bt & (TT - 1);
    float4 a = ((const float4*)te)[(size_t)tok * 64 + c4];
    float4 p = ((const float4*)pe)[(size_t)t * 64 + c4];
    float4 o;
    o.x = a.x + p.x; o.y = a.y + p.y; o.z = a.z + p.z; o.w = a.w + p.w;
    ((float4*)x)[i] = o;
}

// ---------------- layernorm: one wave per row of 256 ----------------
__global__ __launch_bounds__(256)
void ln_kernel(const float* __restrict__ x, const float* __restrict__ g,
               const float* __restrict__ b, float* __restrict__ out) {
    int lane = threadIdx.x & 63;
    int wave = threadIdx.x >> 6;
    int row = blockIdx.x * 4 + wave;
    float4 v = ((const float4*)(x + (size_t)row * CC))[lane];
    float s = v.x + v.y + v.z + v.w;
    #pragma unroll
    for (int m = 1; m < 64; m <<= 1) s += __shfl_xor(s, m, 64);
    float mu = s * (1.f / CC);
    float dx = v.x - mu, dy = v.y - mu, dz = v.z - mu, dw = v.w - mu;
    float vs = dx * dx + dy * dy + dz * dz + dw * dw;
    #pragma unroll
    for (int m = 1; m < 64; m <<= 1) vs += __shfl_xor(vs, m, 64);
    float rs = rsqrtf(vs * (1.f / CC) + 1e-5f);
    float4 gv = ((const float4*)g)[lane];
    float4 bv = ((const float4*)b)[lane];
    float4 o;
    o.x = dx * rs * gv.x + bv.x;
    o.y = dy * rs * gv.y + bv.y;
    o.z = dz * rs * gv.z + bv.z;
    o.w = dw * rs * gv.w + bv.w;
    ((float4*)(out + (size_t)row * CC))[lane] = o;
}

// ---------------- tiled fp32 GEMM: C[M,N] = A[M,K] @ W[K,N] (+bias,+resid,relu) ----
// BM=128 BN=64 BK=16, 256 threads, 8x4 micro-tile
template<bool RELU, bool RESID, bool NB>
__global__ __launch_bounds__(256)
void gemm_k(const float* __restrict__ A, const float* __restrict__ Wt,
            const float* __restrict__ bias, float* __restrict__ Co,
            int N, int K) {
    __shared__ float As[16][132];   // transposed A tile, padded
    __shared__ float Bs[16][64];
    int tid = threadIdx.x;
    int tn = tid & 15, tm = tid >> 4;
    int rowblk = blockIdx.y * 128;
    int colblk = blockIdx.x * 64;
    int arow = tid >> 2, acol = (tid & 3) << 2;
    int brow = tid >> 4, bcol = (tid & 15) << 2;
    float acc[8][4];
    #pragma unroll
    for (int i = 0; i < 8; ++i)
        #pragma unroll
        for (int j = 0; j < 4; ++j) acc[i][j] = 0.f;

    const float* Ab = A + (size_t)rowblk * K;
    for (int k0 = 0; k0 < K; k0 += 16) {
        #pragma unroll
        for (int r = 0; r < 2; ++r) {
            int ar = arow + r * 64;
            float4 av = *(const float4*)(Ab + (size_t)ar * K + k0 + acol);
            As[acol + 0][ar] = av.x;
            As[acol + 1][ar] = av.y;
            As[acol + 2][ar] = av.z;
            As[acol + 3][ar] = av.w;
        }
        {
            int gc = colblk + bcol;
            float4 bv;
            if (!NB) {
                bv = *(const float4*)(Wt + (size_t)(k0 + brow) * N + gc);
            } else {
                const float* wr = Wt + (size_t)(k0 + brow) * N;
                bv.x = (gc + 0 < N) ? wr[gc + 0] : 0.f;
                bv.y = (gc + 1 < N) ? wr[gc + 1] : 0.f;
                bv.z = (gc + 2 < N) ? wr[gc + 2] : 0.f;
                bv.w = (gc + 3 < N) ? wr[gc + 3] : 0.f;
            }
            *(float4*)&Bs[brow][bcol] = bv;
        }
        __syncthreads();
        #pragma unroll
        for (int kk = 0; kk < 16; ++kk) {
            float4 a0 = *(const float4*)&As[kk][tm * 8];
            float4 a1 = *(const float4*)&As[kk][tm * 8 + 4];
            float4 b0 = *(const float4*)&Bs[kk][tn * 4];
            float aa[8] = {a0.x, a0.y, a0.z, a0.w, a1.x, a1.y, a1.z, a1.w};
            float bb[4] = {b0.x, b0.y, b0.z, b0.w};
            #pragma unroll
            for (int i = 0; i < 8; ++i)
                #pragma unroll
                for (int j = 0; j < 4; ++j)
                    acc[i][j] = fmaf(aa[i], bb[j], acc[i][j]);
        }
        __syncthreads();
    }

    int ccol = colblk + tn * 4;
    float bvals[4];
    #pragma unroll
    for (int j = 0; j < 4; ++j)
        bvals[j] = (!NB || (ccol + j) < N) ? bias[ccol + j] : 0.f;
    #pragma unroll
    for (int i = 0; i < 8; ++i) {
        int crow = rowblk + tm * 8 + i;
        float* cp = Co + (size_t)crow * N + ccol;
        float v[4];
        #pragma unroll
        for (int j = 0; j < 4; ++j) v[j] = acc[i][j] + bvals[j];
        if (RESID) {
            if (!NB) {
                float4 rv = *(const float4*)cp;
                v[0] += rv.x; v[1] += rv.y; v[2] += rv.z; v[3] += rv.w;
            } else {
                #pragma unroll
                for (int j = 0; j < 4; ++j)
                    if ((ccol + j) < N) v[j] += cp[j];
            }
        }
        if (RELU) {
            #pragma unroll
            for (int j = 0; j < 4; ++j) v[j] = fmaxf(v[j], 0.f);
        }
        if (!NB) {
            float4 ov; ov.x = v[0]; ov.y = v[1]; ov.z = v[2]; ov.w = v[3];
            *(float4*)cp = ov;
        } else {
            #pragma unroll
            for (int j = 0; j < 4; ++j)
                if ((ccol + j) < N) cp[j] = v[j];
        }
    }
}

// ---------------- attention: one block per (b,h), one query row per thread ----
__global__ __launch_bounds__(256)
void attn_kernel(const float* __restrict__ qkv, float* __restrict__ o) {
    __shared__ float Ks[TT][HSZ];   // 32 KB
    __shared__ float Vs[TT][HSZ];   // 32 KB
    int bh = blockIdx.x;
    int b = bh >> 3, h = bh & 7;
    const float* base = qkv + (size_t)b * TT * 768;
    int tid = threadIdx.x;
    {
        int j = tid >> 3, ch = (tid & 7) * 4;
        #pragma unroll
        for (int r = 0; r < 8; ++r) {
            int row = j + r * 32;
            const float* kr = base + (size_t)row * 768 + 256 + h * 32 + ch;
            const float* vr = base + (size_t)row * 768 + 512 + h * 32 + ch;
            float4 kv = *(const float4*)kr;
            float4 vv = *(const float4*)vr;
            *(float4*)&Ks[row][ch] = kv;
            *(float4*)&Vs[row][ch] = vv;
        }
    }
    __syncthreads();
    int i = tid;   // query row
    const float* qr = base + (size_t)i * 768 + h * 32;
    float4 q[8];
    #pragma unroll
    for (int c = 0; c < 8; ++c) q[c] = ((const float4*)qr)[c];
    float4 acc[8];
    #pragma unroll
    for (int c = 0; c < 8; ++c) { acc[c].x = 0.f; acc[c].y = 0.f; acc[c].z = 0.f; acc[c].w = 0.f; }
    float m = -INFINITY, lsum = 0.f;
    for (int j = 0; j <= i; ++j) {
        const float4* kr = (const float4*)&Ks[j][0];
        float s = 0.f;
        #pragma unroll
        for (int c = 0; c < 8; ++c) {
            float4 kv = kr[c];
            s = fmaf(q[c].x, kv.x, s);
            s = fmaf(q[c].y, kv.y, s);
            s = fmaf(q[c].z, kv.z, s);
            s = fmaf(q[c].w, kv.w, s);
        }
        s *= 0.0625f;   // scale = C^-0.5 = 1/16 (reference uses n_embd, not head_size)
        float mn = fmaxf(m, s);
        float p = __expf(s - mn);
        float corr = __expf(m - mn);   // first iter: exp(-inf)=0
        lsum = lsum * corr + p;
        const float4* vr = (const float4*)&Vs[j][0];
        #pragma unroll
        for (int c = 0; c < 8; ++c) {
            float4 vv = vr[c];
            acc[c].x = fmaf(p, vv.x, acc[c].x * corr);
            acc[c].y = fmaf(p, vv.y, acc[c].y * corr);
            acc[c].z = fmaf(p, vv.z, acc[c].z * corr);
            acc[c].w = fmaf(p, vv.w, acc[c].w * corr);
        }
        m = mn;
    }
    float inv = 1.f / lsum;
    float* orow = o + (size_t)(b * TT + i) * CC + h * 32;
    #pragma unroll
    for (int c = 0; c < 8; ++c) {
        float4 ov;
        ov.x = acc[c].x * inv; ov.y = acc[c].y * inv;
        ov.z = acc[c].z * inv; ov.w = acc[c].w * inv;
        ((float4*)orow)[c] = ov;
    }
}

// ---------------- loss: -mean(log_softmax(logits)[target]) ----------------
__global__ __launch_bounds__(256)
void loss_kernel(const float* __restrict__ lg, const int* __restrict__ tgt,
                 float* __restrict__ loss) {
    int row = blockIdx.x * 256 + threadIdx.x;
    const float* r = lg + (size_t)row * VV;
    float mx = -INFINITY;
    for (int v = 0; v < VV; ++v) mx = fmaxf(mx, r[v]);
    float se = 0.f;
    for (int v = 0; v < VV; ++v) se += __expf(r[v] - mx);
    float nl = mx + __logf(se) - r[tgt[row]];
    #pragma unroll
    for (int m = 1; m < 64; m <<= 1) nl += __shfl_xor(nl, m, 64);
    __shared__ float wsum[4];
    int lane = threadIdx.x & 63, wv = threadIdx.x >> 6;
    if (lane == 0) wsum[wv] = nl;
    __syncthreads();
    if (threadIdx.x == 0) {
        float ssum = wsum[0] + wsum[1] + wsum[2] + wsum[3];
        atomicAdd(loss, ssum * (1.f / BT));
    }
}

// ---------------- dispatch helper ----------------
static void run_gemm(const float* A, const float* W, const float* bias, float* C,
                     int M, int N, int K, bool relu, bool resid, hipStream_t s) {
    dim3 grid((N + 63) / 64, M / 128);
    bool nb = (N & 63) != 0;
    if (nb)         gemm_k<false, false, true ><<<grid, 256, 0, s>>>(A, W, bias, C, N, K);
    else if (relu)  gemm_k<true,  false, false><<<grid, 256, 0, s>>>(A, W, bias, C, N, K);
    else if (resid) gemm_k<false, true,  false><<<grid, 256, 0, s>>>(A, W, bias, C, N, K);
    else            gemm_k<false, false, false><<<grid, 256, 0, s>>>(A, W, bias, C, N, K);
}

extern "C" void kernel_launch(void* const* d_in, const int* in_sizes, int n_in,
                              void* d_out, int out_size, void* d_ws, size_t ws_size,
                              hipStream_t stream) {
    const int*   idx  = (const int*)d_in[0];
    const int*   tgt  = (const int*)d_in[1];
    const float* te   = (const float*)d_in[2];
    const float* pe   = (const float*)d_in[3];
    const float* wq   = (const float*)d_in[4];
    const float* bq   = (const float*)d_in[5];
    const float* wk   = (const float*)d_in[6];
    const float* bk   = (const float*)d_in[7];
    const float* wv   = (const float*)d_in[8];
    const float* bv   = (const float*)d_in[9];
    const float* wo   = (const float*)d_in[10];
    const float* bo   = (const float*)d_in[11];
    const float* ln1g = (const float*)d_in[12];
    const float* ln1b = (const float*)d_in[13];
    const float* w1   = (const float*)d_in[14];
    const float* b1   = (const float*)d_in[15];
    const float* w2   = (const float*)d_in[16];
    const float* b2   = (const float*)d_in[17];
    const float* ln2g = (const float*)d_in[18];
    const float* ln2b = (const float*)d_in[19];
    const float* lnfg = (const float*)d_in[20];
    const float* lnfb = (const float*)d_in[21];
    const float* lmw  = (const float*)d_in[22];
    const float* lmb  = (const float*)d_in[23];
    float* out = (float*)d_out;

    // workspace layout (floats):
    //  x   : BT*C          = 4,194,304
    //  xn  : BT*C          = 4,194,304   (also holds attention output)
    //  buf : BT*1024       = 16,777,216  (qkv [BT,768] then mlp hidden [BT,1024])
    //  Wp  : L*C*768       = 1,179,648
    //  Bp  : L*768         = 4,608
    float* x   = (float*)d_ws;
    float* xn  = x  + (size_t)BT * CC;
    float* buf = xn + (size_t)BT * CC;
    float* Wp  = buf + (size_t)BT * 1024;
    float* Bp  = Wp + (size_t)LL * CC * 768;

    const int totalPack = LL * CC * 768 + LL * 768;
    pack_qkv_kernel<<<(totalPack + 255) / 256, 256, 0, stream>>>(wq, wk, wv, bq, bk, bv, Wp, Bp);
    embed_kernel<<<(BT * 64 + 255) / 256, 256, 0, stream>>>(idx, te, pe, x);

    for (int l = 0; l < LL; ++l) {
        ln_kernel<<<BT / 4, 256, 0, stream>>>(x, ln1g + l * CC, ln1b + l * CC, xn);
        run_gemm(xn, Wp + (size_t)l * CC * 768, Bp + (size_t)l * 768, buf,
                 BT, 768, CC, false, false, stream);
        attn_kernel<<<BB * HH, 256, 0, stream>>>(buf, xn);
        run_gemm(xn, wo + (size_t)l * CC * CC, bo + (size_t)l * CC, x,
                 BT, CC, CC, false, true, stream);
        ln_kernel<<<BT / 4, 256, 0, stream>>>(x, ln2g + l * CC, ln2b + l * CC, xn);
        run_gemm(xn, w1 + (size_t)l * CC * 1024, b1 + (size_t)l * 1024, buf,
                 BT, 1024, CC, true, false, stream);
        run_gemm(buf, w2 + (size_t)l * 1024 * CC, b2 + (size_t)l * CC, x,
                 BT, CC, 1024, false, true, stream);
    }
    ln_kernel<<<BT / 4, 256, 0, stream>>>(x, lnfg, lnfb, xn);
    run_gemm(xn, lmw, lmb, out, BT, VV, CC, false, false, stream);

    hipMemsetAsync(out + (size_t)BT * VV, 0, sizeof(float), stream);
    loss_kernel<<<BT / 256, 256, 0, stream>>>(out, tgt, out + (size_t)BT * VV);
}

// Round 4
// 1581.409 us; speedup vs baseline: 1.7854x; 1.7854x over previous
//
#include <hip/hip_runtime.h>
#include <hip/hip_bf16.h>
#include <math.h>

#define BB 64
#define TT 256
#define CC 256
#define VV 65
#define LL 6
#define HH 8
#define BT (BB*TT)   // 16384

typedef unsigned short u16;
typedef __attribute__((ext_vector_type(8))) short bf8v;     // 8 bf16 (4 VGPRs)
typedef __attribute__((ext_vector_type(4))) float f4v;      // MFMA acc
typedef __attribute__((ext_vector_type(8))) unsigned short u16x8;
typedef __attribute__((ext_vector_type(4))) unsigned short u16x4;

typedef const unsigned int __attribute__((address_space(1))) gu32;
typedef unsigned int       __attribute__((address_space(3))) lu32;

__device__ inline u16 f2bf(float f) {            // round-to-nearest-even bf16
    unsigned u = __float_as_uint(f);
    unsigned r = u + 0x7fffu + ((u >> 16) & 1u);
    return (u16)(r >> 16);
}
__device__ inline float bf2f(u16 h) { return __uint_as_float(((unsigned)h) << 16); }

__device__ inline void gld_lds16(const void* g, void* l) {
    __builtin_amdgcn_global_load_lds((gu32*)g, (lu32*)l, 16, 0, 0);
}

// Tiled operand format: matrix [R, K] -> tiles [R/128][K/64]; tile = 32768 B
//  = hi image (128 rows x 64 bf16, swizzled) then lo image (+16384 B).
//  element (r,k): ushort index r*64 + ((k>>3)^(r&7))*8 + (k&7).

// ---------------- pack weights: W[K][N] -> tiled B^T bf16 hi/lo ----------------
__global__ __launch_bounds__(256)
void pack_std(const float* __restrict__ src, u16* __restrict__ dst,
              int K, int N, int NT, int KT, int L) {
    int id = blockIdx.x * 256 + threadIdx.x;
    int perLayer = NT * KT * 8192;
    if (id >= perLayer * L) return;
    int l = id / perLayer; int rem = id - l * perLayer;
    int tile = rem >> 13;
    int within = rem & 8191;
    int nT = tile / KT, kT = tile - nT * KT;
    int colIn = within >> 6, u = within & 63;
    int sSw = u >> 3, j = u & 7;
    int s = sSw ^ (colIn & 7);
    int k = kT * 64 + s * 8 + j;
    int n = nT * 128 + colIn;
    float v = (n < N) ? src[((size_t)l * K + k) * N + n] : 0.f;
    u16 hi = f2bf(v); u16 lo = f2bf(v - bf2f(hi));
    size_t base = ((size_t)l * NT * KT + tile) * 16384;
    dst[base + within] = hi;
    dst[base + 8192 + within] = lo;
}

// qkv weights: src wq/wk/wv [L][H][C][32] -> packed [K=256][N=768] tiled
__global__ __launch_bounds__(256)
void pack_qkv(const float* __restrict__ wq, const float* __restrict__ wk,
              const float* __restrict__ wv, u16* __restrict__ dst) {
    int id = blockIdx.x * 256 + threadIdx.x;
    const int perLayer = 6 * 4 * 8192;
    if (id >= perLayer * LL) return;
    int l = id / perLayer; int rem = id - l * perLayer;
    int tile = rem >> 13;
    int within = rem & 8191;
    int nT = tile >> 2, kT = tile & 3;
    int colIn = within >> 6, u = within & 63;
    int sSw = u >> 3, j = u & 7;
    int s = sSw ^ (colIn & 7);
    int k = kT * 64 + s * 8 + j;
    int n = nT * 128 + colIn;
    int which = n >> 8, hd = n & 255, h = hd >> 5, d = hd & 31;
    const float* src = (which == 0) ? wq : (which == 1) ? wk : wv;
    float v = src[(((size_t)l * HH + h) * CC + k) * 32 + d];
    u16 hi = f2bf(v); u16 lo = f2bf(v - bf2f(hi));
    size_t base = ((size_t)l * 24 + tile) * 16384;
    dst[base + within] = hi;
    dst[base + 8192 + within] = lo;
}

__global__ __launch_bounds__(256)
void pack_qkv_bias(const float* __restrict__ bq, const float* __restrict__ bk,
                   const float* __restrict__ bv, float* __restrict__ Bp) {
    int e = blockIdx.x * 256 + threadIdx.x;
    if (e >= LL * 768) return;
    int l = e / 768, j = e % 768;
    int which = j >> 8, hd = j & 255, h = hd >> 5, d = hd & 31;
    const float* src = (which == 0) ? bq : (which == 1) ? bk : bv;
    Bp[e] = src[((size_t)l * HH + h) * 32 + d];
}

// ---------------- embedding ----------------
__global__ __launch_bounds__(256)
void embed_kernel(const int* __restrict__ idx, const float* __restrict__ te,
                  const float* __restrict__ pe, float* __restrict__ x) {
    int i = blockIdx.x * blockDim.x + threadIdx.x;
    if (i >= BT * 64) return;
    int bt = i >> 6, c4 = i & 63;
    int tok = idx[bt];
    int t = bt & (TT - 1);
    float4 a = ((const float4*)te)[(size_t)tok * 64 + c4];
    float4 p = ((const float4*)pe)[(size_t)t * 64 + c4];
    float4 o; o.x = a.x + p.x; o.y = a.y + p.y; o.z = a.z + p.z; o.w = a.w + p.w;
    ((float4*)x)[i] = o;
}

// ---------------- layernorm -> tiled bf16 hi/lo ----------------
__global__ __launch_bounds__(256)
void ln_kernel(const float* __restrict__ x, const float* __restrict__ g,
               const float* __restrict__ b, u16* __restrict__ outT) {
    int lane = threadIdx.x & 63;
    int wave = threadIdx.x >> 6;
    int row = blockIdx.x * 4 + wave;
    float4 v = ((const float4*)(x + (size_t)row * CC))[lane];
    float s = v.x + v.y + v.z + v.w;
    #pragma unroll
    for (int m = 1; m < 64; m <<= 1) s += __shfl_xor(s, m, 64);
    float mu = s * (1.f / CC);
    float dx = v.x - mu, dy = v.y - mu, dz = v.z - mu, dw = v.w - mu;
    float vs = dx * dx + dy * dy + dz * dz + dw * dw;
    #pragma unroll
    for (int m = 1; m < 64; m <<= 1) vs += __shfl_xor(vs, m, 64);
    float rs = rsqrtf(vs * (1.f / CC) + 1e-5f);
    float4 gv = ((const float4*)g)[lane];
    float4 bv = ((const float4*)b)[lane];
    float o[4];
    o[0] = dx * rs * gv.x + bv.x;
    o[1] = dy * rs * gv.y + bv.y;
    o[2] = dz * rs * gv.z + bv.z;
    o[3] = dw * rs * gv.w + bv.w;
    int rIn = row & 127, mT = row >> 7;
    int kT = lane >> 4;
    int kIn = (lane * 4) & 63;
    int slot = kIn >> 3, j = kIn & 7;          // j = 0 or 4
    size_t base = ((size_t)mT * 4 + kT) * 16384;
    int ub = rIn * 64 + ((slot ^ (rIn & 7)) << 3) + j;
    u16x4 hi, lo;
    #pragma unroll
    for (int q = 0; q < 4; ++q) {
        hi[q] = f2bf(o[q]);
        lo[q] = f2bf(o[q] - bf2f(hi[q]));
    }
    *(u16x4*)(outT + base + ub) = hi;
    *(u16x4*)(outT + base + 8192 + ub) = lo;
}

// ---------------- MFMA GEMM: C[16384, N] = A @ W  (A,B tiled bf16 hi/lo) -------
// BM=128 BN=128 BK=64, 256 thr (4 waves, 2x2), per-wave 64x64 via 4x4 16x16 frags
// EPI 0: fp32 linear + bias  | 1: + residual | 2: bias+relu -> tiled bf16 | 3: N=65 out
template<int EPI>
__global__ __launch_bounds__(256)
void gemm_mfma(const u16* __restrict__ At, const u16* __restrict__ Bt,
               const float* __restrict__ bias, float* __restrict__ Co,
               u16* __restrict__ CoT, int KT, int NT, int N, int KTout) {
    __shared__ __align__(16) char lds[65536];   // A image 0..32K, B image 32K..64K
    int tid = threadIdx.x;
    int l = tid & 63, w = tid >> 6;
    int nwg = gridDim.x;
    int id = blockIdx.x;
    int cpx = nwg >> 3;                          // all grids are %8==0
    id = (id & 7) * cpx + (id >> 3);             // XCD-contiguous work chunks
    int mT = id / NT, nT = id - mT * NT;

    const char* Abase = (const char*)At + (size_t)mT * KT * 32768;
    const char* Bbase = (const char*)Bt + (size_t)nT * KT * 32768;
    int wm = w >> 1, wn = w & 1;

    f4v acc[4][4];
    #pragma unroll
    for (int i = 0; i < 4; ++i)
        #pragma unroll
        for (int j = 0; j < 4; ++j) acc[i][j] = (f4v)0.f;

    char* la = lds + w * 8192;
    char* lb = lds + 32768 + w * 8192;
    int lrow = l & 15, lg = l >> 4;

    for (int kt = 0; kt < KT; ++kt) {
        const char* ga = Abase + kt * 32768 + w * 8192 + l * 16;
        const char* gb = Bbase + kt * 32768 + w * 8192 + l * 16;
        #pragma unroll
        for (int j = 0; j < 8; ++j) {
            gld_lds16(ga + j * 1024, la + j * 1024);
            gld_lds16(gb + j * 1024, lb + j * 1024);
        }
        __syncthreads();
        #pragma unroll
        for (int kh = 0; kh < 2; ++kh) {
            bf8v ah[4], alv[4], bh[4], blv[4];
            #pragma unroll
            for (int mi = 0; mi < 4; ++mi) {
                int rc = wm * 64 + mi * 16 + lrow;
                int off = rc * 128 + 16 * ((kh * 4 + lg) ^ (rc & 7));
                ah[mi]  = *(const bf8v*)(lds + off);
                alv[mi] = *(const bf8v*)(lds + off + 16384);
            }
            #pragma unroll
            for (int ni = 0; ni < 4; ++ni) {
                int rc = wn * 64 + ni * 16 + lrow;
                int off = 32768 + rc * 128 + 16 * ((kh * 4 + lg) ^ (rc & 7));
                bh[ni]  = *(const bf8v*)(lds + off);
                blv[ni] = *(const bf8v*)(lds + off + 16384);
            }
            #pragma unroll
            for (int mi = 0; mi < 4; ++mi)
                #pragma unroll
                for (int ni = 0; ni < 4; ++ni) {
                    acc[mi][ni] = __builtin_amdgcn_mfma_f32_16x16x32_bf16(ah[mi],  bh[ni],  acc[mi][ni], 0, 0, 0);
                    acc[mi][ni] = __builtin_amdgcn_mfma_f32_16x16x32_bf16(ah[mi],  blv[ni], acc[mi][ni], 0, 0, 0);
                    acc[mi][ni] = __builtin_amdgcn_mfma_f32_16x16x32_bf16(alv[mi], bh[ni],  acc[mi][ni], 0, 0, 0);
                }
        }
        __syncthreads();
    }

    // epilogue: C frag layout col = l&15, row = (l>>4)*4 + q  [m89-verified]
    int colbase = nT * 128 + wn * 64;
    if (EPI == 0 || EPI == 1) {
        #pragma unroll
        for (int mi = 0; mi < 4; ++mi) {
            int r0 = mT * 128 + wm * 64 + mi * 16 + lg * 4;
            #pragma unroll
            for (int ni = 0; ni < 4; ++ni) {
                int cg = colbase + ni * 16 + lrow;
                float bv = bias[cg];
                #pragma unroll
                for (int q = 0; q < 4; ++q) {
                    float f = acc[mi][ni][q] + bv;
                    float* p = Co + (size_t)(r0 + q) * N + cg;
                    if (EPI == 1) f += *p;
                    *p = f;
                }
            }
        }
    } else if (EPI == 2) {
        #pragma unroll
        for (int mi = 0; mi < 4; ++mi) {
            int rr = wm * 64 + mi * 16 + lg * 4;
            #pragma unroll
            for (int ni = 0; ni < 4; ++ni) {
                int cg = colbase + ni * 16 + lrow;
                float bv = bias[cg];
                int kTo = cg >> 6, kIn = cg & 63;
                size_t tbase = ((size_t)mT * KTout + kTo) * 16384;
                #pragma unroll
                for (int q = 0; q < 4; ++q) {
                    int rIn = rr + q;
                    float f = fmaxf(acc[mi][ni][q] + bv, 0.f);
                    u16 hi = f2bf(f);
                    u16 lo = f2bf(f - bf2f(hi));
                    int ub = rIn * 64 + (((kIn >> 3) ^ (rIn & 7)) << 3) + (kIn & 7);
                    CoT[tbase + ub] = hi;
                    CoT[tbase + 8192 + ub] = lo;
                }
            }
        }
    } else {  // EPI 3: lm head, N=65 bounds
        #pragma unroll
        for (int mi = 0; mi < 4; ++mi) {
            int r0 = mT * 128 + wm * 64 + mi * 16 + lg * 4;
            #pragma unroll
            for (int ni = 0; ni < 4; ++ni) {
                int cg = colbase + ni * 16 + lrow;
                if (cg < VV) {
                    float bv = bias[cg];
                    #pragma unroll
                    for (int q = 0; q < 4; ++q)
                        Co[(size_t)(r0 + q) * VV + cg] = acc[mi][ni][q] + bv;
                }
            }
        }
    }
}

// ---------------- attention: block per (b,h), thread per query row -------------
__global__ __launch_bounds__(256)
void attn_kernel(const float* __restrict__ qkv, u16* __restrict__ outT) {
    __shared__ float Ks[TT][32];
    __shared__ float Vs[TT][32];
    int bh = blockIdx.x;
    int b = bh >> 3, h = bh & 7;
    const float* base = qkv + (size_t)b * TT * 768;
    int tid = threadIdx.x;
    {
        int j = tid >> 3, ch = (tid & 7) * 4;
        #pragma unroll
        for (int r = 0; r < 8; ++r) {
            int row = j + r * 32;
            float4 kv = *(const float4*)(base + (size_t)row * 768 + 256 + h * 32 + ch);
            float4 vv = *(const float4*)(base + (size_t)row * 768 + 512 + h * 32 + ch);
            *(float4*)&Ks[row][ch] = kv;
            *(float4*)&Vs[row][ch] = vv;
        }
    }
    __syncthreads();
    int i = tid;
    const float* qr = base + (size_t)i * 768 + h * 32;
    float4 q[8];
    #pragma unroll
    for (int c = 0; c < 8; ++c) q[c] = ((const float4*)qr)[c];
    float4 acc[8];
    #pragma unroll
    for (int c = 0; c < 8; ++c) acc[c] = make_float4(0.f, 0.f, 0.f, 0.f);
    float m = -INFINITY, lsum = 0.f;
    for (int j = 0; j <= i; ++j) {
        const float4* kr = (const float4*)&Ks[j][0];
        float s = 0.f;
        #pragma unroll
        for (int c = 0; c < 8; ++c) {
            float4 kv = kr[c];
            s = fmaf(q[c].x, kv.x, s); s = fmaf(q[c].y, kv.y, s);
            s = fmaf(q[c].z, kv.z, s); s = fmaf(q[c].w, kv.w, s);
        }
        s *= 0.0625f;    // scale = C^-0.5
        float mn = fmaxf(m, s);
        float p = __expf(s - mn);
        float corr = __expf(m - mn);
        lsum = lsum * corr + p;
        const float4* vr = (const float4*)&Vs[j][0];
        #pragma unroll
        for (int c = 0; c < 8; ++c) {
            float4 vv = vr[c];
            acc[c].x = fmaf(p, vv.x, acc[c].x * corr);
            acc[c].y = fmaf(p, vv.y, acc[c].y * corr);
            acc[c].z = fmaf(p, vv.z, acc[c].z * corr);
            acc[c].w = fmaf(p, vv.w, acc[c].w * corr);
        }
        m = mn;
    }
    float inv = 1.f / lsum;
    // epilogue: write tiled bf16 hi/lo (features h*32 .. h*32+31)
    int rIn = i & 127;
    int mT = b * 2 + (i >> 7);
    int kT = h >> 1;
    size_t tbase = ((size_t)mT * 4 + kT) * 16384;
    float af[32];
    #pragma unroll
    for (int c = 0; c < 8; ++c) {
        af[c * 4 + 0] = acc[c].x * inv; af[c * 4 + 1] = acc[c].y * inv;
        af[c * 4 + 2] = acc[c].z * inv; af[c * 4 + 3] = acc[c].w * inv;
    }
    #pragma unroll
    for (int s4 = 0; s4 < 4; ++s4) {
        int kIn = (h & 1) * 32 + s4 * 8;
        int slot = kIn >> 3;
        int ub = rIn * 64 + ((slot ^ (rIn & 7)) << 3);
        u16x8 hi, lo;
        #pragma unroll
        for (int jj = 0; jj < 8; ++jj) {
            float f = af[s4 * 8 + jj];
            hi[jj] = f2bf(f);
            lo[jj] = f2bf(f - bf2f(hi[jj]));
        }
        *(u16x8*)(outT + tbase + ub) = hi;
        *(u16x8*)(outT + tbase + 8192 + ub) = lo;
    }
}

// ---------------- loss ----------------
__global__ __launch_bounds__(256)
void loss_kernel(const float* __restrict__ lg, const int* __restrict__ tgt,
                 float* __restrict__ loss) {
    int row = blockIdx.x * 256 + threadIdx.x;
    const float* r = lg + (size_t)row * VV;
    float mx = -INFINITY;
    for (int v = 0; v < VV; ++v) mx = fmaxf(mx, r[v]);
    float se = 0.f;
    for (int v = 0; v < VV; ++v) se += __expf(r[v] - mx);
    float nl = mx + __logf(se) - r[tgt[row]];
    #pragma unroll
    for (int m = 1; m < 64; m <<= 1) nl += __shfl_xor(nl, m, 64);
    __shared__ float wsum[4];
    int lane = threadIdx.x & 63, wv = threadIdx.x >> 6;
    if (lane == 0) wsum[wv] = nl;
    __syncthreads();
    if (threadIdx.x == 0)
        atomicAdd(loss, (wsum[0] + wsum[1] + wsum[2] + wsum[3]) * (1.f / BT));
}

// ---------------- host-side dispatch ----------------
template<int EPI>
static void launch_gemm(const u16* At, const u16* Bt, const float* bias,
                        float* Co, u16* CoT, int KT, int NT, int N, int KTout,
                        hipStream_t s) {
    gemm_mfma<EPI><<<dim3(128 * NT), 256, 0, s>>>(At, Bt, bias, Co, CoT, KT, NT, N, KTout);
}

extern "C" void kernel_launch(void* const* d_in, const int* in_sizes, int n_in,
                              void* d_out, int out_size, void* d_ws, size_t ws_size,
                              hipStream_t stream) {
    const int*   idx  = (const int*)d_in[0];
    const int*   tgt  = (const int*)d_in[1];
    const float* te   = (const float*)d_in[2];
    const float* pe   = (const float*)d_in[3];
    const float* wq   = (const float*)d_in[4];
    const float* bq   = (const float*)d_in[5];
    const float* wk   = (const float*)d_in[6];
    const float* bk   = (const float*)d_in[7];
    const float* wv   = (const float*)d_in[8];
    const float* bv   = (const float*)d_in[9];
    const float* wo   = (const float*)d_in[10];
    const float* bo   = (const float*)d_in[11];
    const float* ln1g = (const float*)d_in[12];
    const float* ln1b = (const float*)d_in[13];
    const float* w1   = (const float*)d_in[14];
    const float* b1   = (const float*)d_in[15];
    const float* w2   = (const float*)d_in[16];
    const float* b2   = (const float*)d_in[17];
    const float* ln2g = (const float*)d_in[18];
    const float* ln2b = (const float*)d_in[19];
    const float* lnfg = (const float*)d_in[20];
    const float* lnfb = (const float*)d_in[21];
    const float* lmw  = (const float*)d_in[22];
    const float* lmb  = (const float*)d_in[23];
    float* out = (float*)d_out;

    // workspace layout (bytes)
    char* base = (char*)d_ws;
    float* x       = (float*)(base);                       // 16,777,216
    float* qkvbuf  = (float*)(base + 16777216);            // shares 67,108,864 with hiddenT
    u16*   hiddenT = (u16*)  (base + 16777216);
    u16*   xnT     = (u16*)  (base + 83886080);            // 16,777,216
    u16*   qkvT    = (u16*)  (base + 100663296);           //  4,718,592
    u16*   woT     = (u16*)  (base + 105381888);           //  1,572,864
    u16*   w1T     = (u16*)  (base + 106954752);           //  6,291,456
    u16*   w2T     = (u16*)  (base + 113246208);           //  6,291,456
    u16*   lmT     = (u16*)  (base + 119537664);           //    131,072
    float* Bp      = (float*)(base + 119668736);           //     18,432

    // pack weights (per-launch; weights restored by harness each call)
    pack_qkv<<<dim3((LL * 6 * 4 * 8192) / 256), 256, 0, stream>>>(wq, wk, wv, qkvT);
    pack_std<<<dim3((LL * 2 * 4 * 8192) / 256), 256, 0, stream>>>(wo, woT, 256, 256, 2, 4, LL);
    pack_std<<<dim3((LL * 8 * 4 * 8192) / 256), 256, 0, stream>>>(w1, w1T, 256, 1024, 8, 4, LL);
    pack_std<<<dim3((LL * 2 * 16 * 8192) / 256), 256, 0, stream>>>(w2, w2T, 1024, 256, 2, 16, LL);
    pack_std<<<dim3((1 * 1 * 4 * 8192) / 256), 256, 0, stream>>>(lmw, lmT, 256, VV, 1, 4, 1);
    pack_qkv_bias<<<dim3((LL * 768 + 255) / 256), 256, 0, stream>>>(bq, bk, bv, Bp);

    embed_kernel<<<dim3((BT * 64) / 256), 256, 0, stream>>>(idx, te, pe, x);

    for (int l = 0; l < LL; ++l) {
        ln_kernel<<<dim3(BT / 4), 256, 0, stream>>>(x, ln1g + l * CC, ln1b + l * CC, xnT);
        launch_gemm<0>(xnT, qkvT + (size_t)l * 393216, Bp + l * 768,
                       qkvbuf, nullptr, 4, 6, 768, 0, stream);
        attn_kernel<<<dim3(BB * HH), 256, 0, stream>>>(qkvbuf, xnT);
        launch_gemm<1>(xnT, woT + (size_t)l * 131072, bo + l * CC,
                       x, nullptr, 4, 2, 256, 0, stream);
        ln_kernel<<<dim3(BT / 4), 256, 0, stream>>>(x, ln2g + l * CC, ln2b + l * CC, xnT);
        launch_gemm<2>(xnT, w1T + (size_t)l * 524288, b1 + l * 1024,
                       nullptr, hiddenT, 4, 8, 1024, 16, stream);
        launch_gemm<1>(hiddenT, w2T + (size_t)l * 524288, b2 + l * CC,
                       x, nullptr, 16, 2, 256, 0, stream);
    }
    ln_kernel<<<dim3(BT / 4), 256, 0, stream>>>(x, lnfg, lnfb, xnT);
    launch_gemm<3>(xnT, lmT, lmb, out, nullptr, 4, 1, VV, 0, stream);

    hipMemsetAsync(out + (size_t)BT * VV, 0, sizeof(float), stream);
    loss_kernel<<<dim3(BT / 256), 256, 0, stream>>>(out, tgt, out + (size_t)BT * VV);
}

// Round 5
// 1208.575 us; speedup vs baseline: 2.3361x; 1.3085x over previous
//
#include <hip/hip_runtime.h>
#include <hip/hip_bf16.h>
#include <math.h>

#define BB 64
#define TT 256
#define CC 256
#define VV 65
#define LL 6
#define HH 8
#define BT (BB*TT)   // 16384

typedef unsigned short u16;
typedef __attribute__((ext_vector_type(8))) short bf8v;     // 8 bf16 (4 VGPRs)
typedef __attribute__((ext_vector_type(4))) float f4v;      // MFMA acc
typedef __attribute__((ext_vector_type(8))) unsigned short u16x8;
typedef __attribute__((ext_vector_type(4))) unsigned short u16x4;

typedef const unsigned int __attribute__((address_space(1))) gu32;
typedef unsigned int       __attribute__((address_space(3))) lu32;

__device__ inline u16 f2bf(float f) {            // round-to-nearest-even bf16
    unsigned u = __float_as_uint(f);
    unsigned r = u + 0x7fffu + ((u >> 16) & 1u);
    return (u16)(r >> 16);
}
__device__ inline float bf2f(u16 h) { return __uint_as_float(((unsigned)h) << 16); }

__device__ inline void gld_lds16(const void* g, void* l) {
    __builtin_amdgcn_global_load_lds((gu32*)g, (lu32*)l, 16, 0, 0);
}

// Tiled operand format: matrix [R, K] -> tiles [R/128][K/64]; tile = 32768 B
//  = hi image (128 rows x 64 bf16, swizzled) then lo image (+16384 B).
//  element (r,k): ushort index r*64 + ((k>>3)^(r&7))*8 + (k&7).

// ---------------- pack weights: W[K][N] -> tiled B^T bf16 hi/lo ----------------
__global__ __launch_bounds__(256)
void pack_std(const float* __restrict__ src, u16* __restrict__ dst,
              int K, int N, int NT, int KT, int L) {
    int id = blockIdx.x * 256 + threadIdx.x;
    int perLayer = NT * KT * 8192;
    if (id >= perLayer * L) return;
    int l = id / perLayer; int rem = id - l * perLayer;
    int tile = rem >> 13;
    int within = rem & 8191;
    int nT = tile / KT, kT = tile - nT * KT;
    int colIn = within >> 6, u = within & 63;
    int sSw = u >> 3, j = u & 7;
    int s = sSw ^ (colIn & 7);
    int k = kT * 64 + s * 8 + j;
    int n = nT * 128 + colIn;
    float v = (n < N) ? src[((size_t)l * K + k) * N + n] : 0.f;
    u16 hi = f2bf(v); u16 lo = f2bf(v - bf2f(hi));
    size_t base = ((size_t)l * NT * KT + tile) * 16384;
    dst[base + within] = hi;
    dst[base + 8192 + within] = lo;
}

// qkv weights: src wq/wk/wv [L][H][C][32] -> packed [K=256][N=768] tiled
__global__ __launch_bounds__(256)
void pack_qkv(const float* __restrict__ wq, const float* __restrict__ wk,
              const float* __restrict__ wv, u16* __restrict__ dst) {
    int id = blockIdx.x * 256 + threadIdx.x;
    const int perLayer = 6 * 4 * 8192;
    if (id >= perLayer * LL) return;
    int l = id / perLayer; int rem = id - l * perLayer;
    int tile = rem >> 13;
    int within = rem & 8191;
    int nT = tile >> 2, kT = tile & 3;
    int colIn = within >> 6, u = within & 63;
    int sSw = u >> 3, j = u & 7;
    int s = sSw ^ (colIn & 7);
    int k = kT * 64 + s * 8 + j;
    int n = nT * 128 + colIn;
    int which = n >> 8, hd = n & 255, h = hd >> 5, d = hd & 31;
    const float* src = (which == 0) ? wq : (which == 1) ? wk : wv;
    float v = src[(((size_t)l * HH + h) * CC + k) * 32 + d];
    u16 hi = f2bf(v); u16 lo = f2bf(v - bf2f(hi));
    size_t base = ((size_t)l * 24 + tile) * 16384;
    dst[base + within] = hi;
    dst[base + 8192 + within] = lo;
}

__global__ __launch_bounds__(256)
void pack_qkv_bias(const float* __restrict__ bq, const float* __restrict__ bk,
                   const float* __restrict__ bv, float* __restrict__ Bp) {
    int e = blockIdx.x * 256 + threadIdx.x;
    if (e >= LL * 768) return;
    int l = e / 768, j = e % 768;
    int which = j >> 8, hd = j & 255, h = hd >> 5, d = hd & 31;
    const float* src = (which == 0) ? bq : (which == 1) ? bk : bv;
    Bp[e] = src[((size_t)l * HH + h) * 32 + d];
}

// ---------------- embedding ----------------
__global__ __launch_bounds__(256)
void embed_kernel(const int* __restrict__ idx, const float* __restrict__ te,
                  const float* __restrict__ pe, float* __restrict__ x) {
    int i = blockIdx.x * blockDim.x + threadIdx.x;
    if (i >= BT * 64) return;
    int bt = i >> 6, c4 = i & 63;
    int tok = idx[bt];
    int t = bt & (TT - 1);
    float4 a = ((const float4*)te)[(size_t)tok * 64 + c4];
    float4 p = ((const float4*)pe)[(size_t)t * 64 + c4];
    float4 o; o.x = a.x + p.x; o.y = a.y + p.y; o.z = a.z + p.z; o.w = a.w + p.w;
    ((float4*)x)[i] = o;
}

// ---------------- layernorm -> tiled bf16 hi/lo ----------------
__global__ __launch_bounds__(256)
void ln_kernel(const float* __restrict__ x, const float* __restrict__ g,
               const float* __restrict__ b, u16* __restrict__ outT) {
    int lane = threadIdx.x & 63;
    int wave = threadIdx.x >> 6;
    int row = blockIdx.x * 4 + wave;
    float4 v = ((const float4*)(x + (size_t)row * CC))[lane];
    float s = v.x + v.y + v.z + v.w;
    #pragma unroll
    for (int m = 1; m < 64; m <<= 1) s += __shfl_xor(s, m, 64);
    float mu = s * (1.f / CC);
    float dx = v.x - mu, dy = v.y - mu, dz = v.z - mu, dw = v.w - mu;
    float vs = dx * dx + dy * dy + dz * dz + dw * dw;
    #pragma unroll
    for (int m = 1; m < 64; m <<= 1) vs += __shfl_xor(vs, m, 64);
    float rs = rsqrtf(vs * (1.f / CC) + 1e-5f);
    float4 gv = ((const float4*)g)[lane];
    float4 bv = ((const float4*)b)[lane];
    float o[4];
    o[0] = dx * rs * gv.x + bv.x;
    o[1] = dy * rs * gv.y + bv.y;
    o[2] = dz * rs * gv.z + bv.z;
    o[3] = dw * rs * gv.w + bv.w;
    int rIn = row & 127, mT = row >> 7;
    int kT = lane >> 4;
    int kIn = (lane * 4) & 63;
    int slot = kIn >> 3, j = kIn & 7;          // j = 0 or 4
    size_t base = ((size_t)mT * 4 + kT) * 16384;
    int ub = rIn * 64 + ((slot ^ (rIn & 7)) << 3) + j;
    u16x4 hi, lo;
    #pragma unroll
    for (int q = 0; q < 4; ++q) {
        hi[q] = f2bf(o[q]);
        lo[q] = f2bf(o[q] - bf2f(hi[q]));
    }
    *(u16x4*)(outT + base + ub) = hi;
    *(u16x4*)(outT + base + 8192 + ub) = lo;
}

// ---------------- MFMA GEMM: C[16384, N] = A @ W  (A,B tiled bf16 hi/lo) -------
// BM=128 BN=128 BK=64, 256 thr (4 waves, 2x2), per-wave 64x64 via 4x4 16x16 frags
// EPI 0: fp32 linear + bias  | 1: + residual | 2: bias+relu -> tiled bf16 | 3: N=65 out
template<int EPI>
__global__ __launch_bounds__(256)
void gemm_mfma(const u16* __restrict__ At, const u16* __restrict__ Bt,
               const float* __restrict__ bias, float* __restrict__ Co,
               u16* __restrict__ CoT, int KT, int NT, int N, int KTout) {
    __shared__ __align__(16) char lds[65536];   // A image 0..32K, B image 32K..64K
    int tid = threadIdx.x;
    int l = tid & 63, w = tid >> 6;
    int nwg = gridDim.x;
    int id = blockIdx.x;
    int cpx = nwg >> 3;                          // all grids are %8==0
    id = (id & 7) * cpx + (id >> 3);             // XCD-contiguous work chunks
    int mT = id / NT, nT = id - mT * NT;

    const char* Abase = (const char*)At + (size_t)mT * KT * 32768;
    const char* Bbase = (const char*)Bt + (size_t)nT * KT * 32768;
    int wm = w >> 1, wn = w & 1;

    f4v acc[4][4];
    #pragma unroll
    for (int i = 0; i < 4; ++i)
        #pragma unroll
        for (int j = 0; j < 4; ++j) acc[i][j] = (f4v)0.f;

    char* la = lds + w * 8192;
    char* lb = lds + 32768 + w * 8192;
    int lrow = l & 15, lg = l >> 4;

    for (int kt = 0; kt < KT; ++kt) {
        const char* ga = Abase + kt * 32768 + w * 8192 + l * 16;
        const char* gb = Bbase + kt * 32768 + w * 8192 + l * 16;
        #pragma unroll
        for (int j = 0; j < 8; ++j) {
            gld_lds16(ga + j * 1024, la + j * 1024);
            gld_lds16(gb + j * 1024, lb + j * 1024);
        }
        __syncthreads();
        #pragma unroll
        for (int kh = 0; kh < 2; ++kh) {
            bf8v ah[4], alv[4], bh[4], blv[4];
            #pragma unroll
            for (int mi = 0; mi < 4; ++mi) {
                int rc = wm * 64 + mi * 16 + lrow;
                int off = rc * 128 + 16 * ((kh * 4 + lg) ^ (rc & 7));
                ah[mi]  = *(const bf8v*)(lds + off);
                alv[mi] = *(const bf8v*)(lds + off + 16384);
            }
            #pragma unroll
            for (int ni = 0; ni < 4; ++ni) {
                int rc = wn * 64 + ni * 16 + lrow;
                int off = 32768 + rc * 128 + 16 * ((kh * 4 + lg) ^ (rc & 7));
                bh[ni]  = *(const bf8v*)(lds + off);
                blv[ni] = *(const bf8v*)(lds + off + 16384);
            }
            #pragma unroll
            for (int mi = 0; mi < 4; ++mi)
                #pragma unroll
                for (int ni = 0; ni < 4; ++ni) {
                    acc[mi][ni] = __builtin_amdgcn_mfma_f32_16x16x32_bf16(ah[mi],  bh[ni],  acc[mi][ni], 0, 0, 0);
                    acc[mi][ni] = __builtin_amdgcn_mfma_f32_16x16x32_bf16(ah[mi],  blv[ni], acc[mi][ni], 0, 0, 0);
                    acc[mi][ni] = __builtin_amdgcn_mfma_f32_16x16x32_bf16(alv[mi], bh[ni],  acc[mi][ni], 0, 0, 0);
                }
        }
        __syncthreads();
    }

    // epilogue: C frag layout col = l&15, row = (l>>4)*4 + q  [m89-verified]
    int colbase = nT * 128 + wn * 64;
    if (EPI == 0 || EPI == 1) {
        #pragma unroll
        for (int mi = 0; mi < 4; ++mi) {
            int r0 = mT * 128 + wm * 64 + mi * 16 + lg * 4;
            #pragma unroll
            for (int ni = 0; ni < 4; ++ni) {
                int cg = colbase + ni * 16 + lrow;
                float bv = bias[cg];
                #pragma unroll
                for (int q = 0; q < 4; ++q) {
                    float f = acc[mi][ni][q] + bv;
                    float* p = Co + (size_t)(r0 + q) * N + cg;
                    if (EPI == 1) f += *p;
                    *p = f;
                }
            }
        }
    } else if (EPI == 2) {
        #pragma unroll
        for (int mi = 0; mi < 4; ++mi) {
            int rr = wm * 64 + mi * 16 + lg * 4;
            #pragma unroll
            for (int ni = 0; ni < 4; ++ni) {
                int cg = colbase + ni * 16 + lrow;
                float bv = bias[cg];
                int kTo = cg >> 6, kIn = cg & 63;
                size_t tbase = ((size_t)mT * KTout + kTo) * 16384;
                #pragma unroll
                for (int q = 0; q < 4; ++q) {
                    int rIn = rr + q;
                    float f = fmaxf(acc[mi][ni][q] + bv, 0.f);
                    u16 hi = f2bf(f);
                    u16 lo = f2bf(f - bf2f(hi));
                    int ub = rIn * 64 + (((kIn >> 3) ^ (rIn & 7)) << 3) + (kIn & 7);
                    CoT[tbase + ub] = hi;
                    CoT[tbase + 8192 + ub] = lo;
                }
            }
        }
    } else {  // EPI 3: lm head, N=65 bounds
        #pragma unroll
        for (int mi = 0; mi < 4; ++mi) {
            int r0 = mT * 128 + wm * 64 + mi * 16 + lg * 4;
            #pragma unroll
            for (int ni = 0; ni < 4; ++ni) {
                int cg = colbase + ni * 16 + lrow;
                if (cg < VV) {
                    float bv = bias[cg];
                    #pragma unroll
                    for (int q = 0; q < 4; ++q)
                        Co[(size_t)(r0 + q) * VV + cg] = acc[mi][ni][q] + bv;
                }
            }
        }
    }
}

// ---------------- MFMA flash attention: block per (b,h), 4 waves ----------------
// LDS: K bf16 [256 rows][80B] @0 ; V^T bf16 [32 rows][528B] @20480 ;
//      P per wave [16 rows][80B] @37376 + w*1280.  Total 42496 B.
// Wave w owns m-tiles {w, 7-w, 8+w, 15-w} (balanced causal work).
// Assumed k-mapping f(g,j)=8g+j used consistently on BOTH operands of each MFMA
// (any bijective deviation of true HW layout cancels).
__global__ __launch_bounds__(256)
void attn_mfma(const float* __restrict__ qkv, u16* __restrict__ outT) {
    __shared__ __align__(16) char lds[42496];
    int bh = blockIdx.x;
    bh = (bh & 7) * 64 + (bh >> 3);      // bijective XCD swizzle (512 = 8*64)
    int b = bh >> 3, h = bh & 7;
    const float* base = qkv + (size_t)b * TT * 768;
    int tid = threadIdx.x;
    int w = tid >> 6, l = tid & 63;
    int li = l & 15, g = l >> 4;

    // ---- stage K (row-major) and V^T ----
    {
        int r0 = tid >> 3, c = tid & 7;          // 32 rows / iter, 8 float4-chunks
        #pragma unroll
        for (int it = 0; it < 8; ++it) {
            int t = it * 32 + r0;
            float4 kv = *(const float4*)(base + (size_t)t * 768 + 256 + h * 32 + c * 4);
            float4 vv = *(const float4*)(base + (size_t)t * 768 + 512 + h * 32 + c * 4);
            u16x4 kh;
            kh[0] = f2bf(kv.x); kh[1] = f2bf(kv.y); kh[2] = f2bf(kv.z); kh[3] = f2bf(kv.w);
            *(u16x4*)(lds + t * 80 + c * 8) = kh;
            u16 vh0 = f2bf(vv.x), vh1 = f2bf(vv.y), vh2 = f2bf(vv.z), vh3 = f2bf(vv.w);
            *(u16*)(lds + 20480 + (c * 4 + 0) * 528 + t * 2) = vh0;
            *(u16*)(lds + 20480 + (c * 4 + 1) * 528 + t * 2) = vh1;
            *(u16*)(lds + 20480 + (c * 4 + 2) * 528 + t * 2) = vh2;
            *(u16*)(lds + 20480 + (c * 4 + 3) * 528 + t * 2) = vh3;
        }
    }
    __syncthreads();

    char* Pb = lds + 37376 + w * 1280;
    int mts[4] = {w, 7 - w, 8 + w, 15 - w};
    #pragma unroll
    for (int im = 0; im < 4; ++im) {
        int mt = mts[im];
        int mq = mt * 16;
        // Q fragment: row li, d = 8g..8g+7
        const float* qp = base + (size_t)(mq + li) * 768 + h * 32 + g * 8;
        float4 q0 = *(const float4*)qp;
        float4 q1 = *(const float4*)(qp + 4);
        bf8v aq;
        aq[0] = (short)f2bf(q0.x); aq[1] = (short)f2bf(q0.y);
        aq[2] = (short)f2bf(q0.z); aq[3] = (short)f2bf(q0.w);
        aq[4] = (short)f2bf(q1.x); aq[5] = (short)f2bf(q1.y);
        aq[6] = (short)f2bf(q1.z); aq[7] = (short)f2bf(q1.w);

        f4v o0 = (f4v)0.f, o1 = (f4v)0.f;
        float mrun0 = -1e30f, mrun1 = -1e30f, mrun2 = -1e30f, mrun3 = -1e30f;
        float lrun0 = 0.f, lrun1 = 0.f, lrun2 = 0.f, lrun3 = 0.f;
        int nu = (mt >> 1) + 1;
        for (int kt = 0; kt < nu; ++kt) {
            int kb = kt * 32;
            bf8v kf0 = *(const bf8v*)(lds + (kb + li) * 80 + g * 16);
            bf8v kf1 = *(const bf8v*)(lds + (kb + 16 + li) * 80 + g * 16);
            f4v s0 = __builtin_amdgcn_mfma_f32_16x16x32_bf16(aq, kf0, (f4v)0.f, 0, 0, 0);
            f4v s1 = __builtin_amdgcn_mfma_f32_16x16x32_bf16(aq, kf1, (f4v)0.f, 0, 0, 0);
            bool maskunit = (kt == nu - 1);
            float p0[4], p1[4];
            float* mr[4] = {&mrun0, &mrun1, &mrun2, &mrun3};
            float* lr[4] = {&lrun0, &lrun1, &lrun2, &lrun3};
            #pragma unroll
            for (int qq = 0; qq < 4; ++qq) {
                float v0 = s0[qq] * 0.0625f;     // scale = C^-0.5 = 1/16
                float v1 = s1[qq] * 0.0625f;
                if (maskunit) {
                    int qg = mq + g * 4 + qq;
                    if (kb + li > qg)      v0 = -1e30f;
                    if (kb + 16 + li > qg) v1 = -1e30f;
                }
                float tm = fmaxf(v0, v1);
                #pragma unroll
                for (int msk = 1; msk < 16; msk <<= 1)
                    tm = fmaxf(tm, __shfl_xor(tm, msk, 64));
                float mold = *mr[qq];
                float mnew = fmaxf(mold, tm);
                float corr = __expf(mold - mnew);
                float e0 = __expf(v0 - mnew);
                float e1 = __expf(v1 - mnew);
                float ts = e0 + e1;
                #pragma unroll
                for (int msk = 1; msk < 16; msk <<= 1)
                    ts += __shfl_xor(ts, msk, 64);
                *lr[qq] = *lr[qq] * corr + ts;
                *mr[qq] = mnew;
                o0[qq] *= corr; o1[qq] *= corr;
                p0[qq] = e0; p1[qq] = e1;
            }
            // P -> LDS in [q][s] layout (C-frag: row q = 4g+qq, col s = li)
            #pragma unroll
            for (int qq = 0; qq < 4; ++qq) {
                *(u16*)(Pb + (g * 4 + qq) * 80 + li * 2)        = f2bf(p0[qq]);
                *(u16*)(Pb + (g * 4 + qq) * 80 + (16 + li) * 2) = f2bf(p1[qq]);
            }
            bf8v pf  = *(const bf8v*)(Pb + li * 80 + g * 16);
            bf8v vf0 = *(const bf8v*)(lds + 20480 + li * 528        + kb * 2 + g * 16);
            bf8v vf1 = *(const bf8v*)(lds + 20480 + (16 + li) * 528 + kb * 2 + g * 16);
            o0 = __builtin_amdgcn_mfma_f32_16x16x32_bf16(pf, vf0, o0, 0, 0, 0);
            o1 = __builtin_amdgcn_mfma_f32_16x16x32_bf16(pf, vf1, o1, 0, 0, 0);
        }
        // epilogue: token = b*256 + mq + 4g+qq; feature = h*32 + dsub*16 + li
        float inv0 = 1.f / lrun0, inv1 = 1.f / lrun1, inv2 = 1.f / lrun2, inv3 = 1.f / lrun3;
        float invs[4] = {inv0, inv1, inv2, inv3};
        #pragma unroll
        for (int qq = 0; qq < 4; ++qq) {
            int tok = mq + g * 4 + qq;
            int rIn = tok & 127;
            size_t tb = ((size_t)(b * 2 + (tok >> 7)) * 4 + (h >> 1)) * 16384;
            float f0 = o0[qq] * invs[qq];
            float f1 = o1[qq] * invs[qq];
            int kIn0 = (h & 1) * 32 + li;
            int kIn1 = kIn0 + 16;
            int ub0 = rIn * 64 + (((kIn0 >> 3) ^ (rIn & 7)) << 3) + (kIn0 & 7);
            int ub1 = rIn * 64 + (((kIn1 >> 3) ^ (rIn & 7)) << 3) + (kIn1 & 7);
            u16 h0 = f2bf(f0);
            outT[tb + ub0] = h0;
            outT[tb + 8192 + ub0] = f2bf(f0 - bf2f(h0));
            u16 h1 = f2bf(f1);
            outT[tb + ub1] = h1;
            outT[tb + 8192 + ub1] = f2bf(f1 - bf2f(h1));
        }
    }
}

// ---------------- loss ----------------
__global__ __launch_bounds__(256)
void loss_kernel(const float* __restrict__ lg, const int* __restrict__ tgt,
                 float* __restrict__ loss) {
    int row = blockIdx.x * 256 + threadIdx.x;
    const float* r = lg + (size_t)row * VV;
    float mx = -INFINITY;
    for (int v = 0; v < VV; ++v) mx = fmaxf(mx, r[v]);
    float se = 0.f;
    for (int v = 0; v < VV; ++v) se += __expf(r[v] - mx);
    float nl = mx + __logf(se) - r[tgt[row]];
    #pragma unroll
    for (int m = 1; m < 64; m <<= 1) nl += __shfl_xor(nl, m, 64);
    __shared__ float wsum[4];
    int lane = threadIdx.x & 63, wv = threadIdx.x >> 6;
    if (lane == 0) wsum[wv] = nl;
    __syncthreads();
    if (threadIdx.x == 0)
        atomicAdd(loss, (wsum[0] + wsum[1] + wsum[2] + wsum[3]) * (1.f / BT));
}

// ---------------- host-side dispatch ----------------
template<int EPI>
static void launch_gemm(const u16* At, const u16* Bt, const float* bias,
                        float* Co, u16* CoT, int KT, int NT, int N, int KTout,
                        hipStream_t s) {
    gemm_mfma<EPI><<<dim3(128 * NT), 256, 0, s>>>(At, Bt, bias, Co, CoT, KT, NT, N, KTout);
}

extern "C" void kernel_launch(void* const* d_in, const int* in_sizes, int n_in,
                              void* d_out, int out_size, void* d_ws, size_t ws_size,
                              hipStream_t stream) {
    const int*   idx  = (const int*)d_in[0];
    const int*   tgt  = (const int*)d_in[1];
    const float* te   = (const float*)d_in[2];
    const float* pe   = (const float*)d_in[3];
    const float* wq   = (const float*)d_in[4];
    const float* bq   = (const float*)d_in[5];
    const float* wk   = (const float*)d_in[6];
    const float* bk   = (const float*)d_in[7];
    const float* wv   = (const float*)d_in[8];
    const float* bv   = (const float*)d_in[9];
    const float* wo   = (const float*)d_in[10];
    const float* bo   = (const float*)d_in[11];
    const float* ln1g = (const float*)d_in[12];
    const float* ln1b = (const float*)d_in[13];
    const float* w1   = (const float*)d_in[14];
    const float* b1   = (const float*)d_in[15];
    const float* w2   = (const float*)d_in[16];
    const float* b2   = (const float*)d_in[17];
    const float* ln2g = (const float*)d_in[18];
    const float* ln2b = (const float*)d_in[19];
    const float* lnfg = (const float*)d_in[20];
    const float* lnfb = (const float*)d_in[21];
    const float* lmw  = (const float*)d_in[22];
    const float* lmb  = (const float*)d_in[23];
    float* out = (float*)d_out;

    // workspace layout (bytes)
    char* base = (char*)d_ws;
    float* x       = (float*)(base);                       // 16,777,216
    float* qkvbuf  = (float*)(base + 16777216);            // shares 67,108,864 with hiddenT
    u16*   hiddenT = (u16*)  (base + 16777216);
    u16*   xnT     = (u16*)  (base + 83886080);            // 16,777,216
    u16*   qkvT    = (u16*)  (base + 100663296);           //  4,718,592
    u16*   woT     = (u16*)  (base + 105381888);           //  1,572,864
    u16*   w1T     = (u16*)  (base + 106954752);           //  6,291,456
    u16*   w2T     = (u16*)  (base + 113246208);           //  6,291,456
    u16*   lmT     = (u16*)  (base + 119537664);           //    131,072
    float* Bp      = (float*)(base + 119668736);           //     18,432

    // pack weights (per-launch; weights restored by harness each call)
    pack_qkv<<<dim3((LL * 6 * 4 * 8192) / 256), 256, 0, stream>>>(wq, wk, wv, qkvT);
    pack_std<<<dim3((LL * 2 * 4 * 8192) / 256), 256, 0, stream>>>(wo, woT, 256, 256, 2, 4, LL);
    pack_std<<<dim3((LL * 8 * 4 * 8192) / 256), 256, 0, stream>>>(w1, w1T, 256, 1024, 8, 4, LL);
    pack_std<<<dim3((LL * 2 * 16 * 8192) / 256), 256, 0, stream>>>(w2, w2T, 1024, 256, 2, 16, LL);
    pack_std<<<dim3((1 * 1 * 4 * 8192) / 256), 256, 0, stream>>>(lmw, lmT, 256, VV, 1, 4, 1);
    pack_qkv_bias<<<dim3((LL * 768 + 255) / 256), 256, 0, stream>>>(bq, bk, bv, Bp);

    embed_kernel<<<dim3((BT * 64) / 256), 256, 0, stream>>>(idx, te, pe, x);

    for (int l = 0; l < LL; ++l) {
        ln_kernel<<<dim3(BT / 4), 256, 0, stream>>>(x, ln1g + l * CC, ln1b + l * CC, xnT);
        launch_gemm<0>(xnT, qkvT + (size_t)l * 393216, Bp + l * 768,
                       qkvbuf, nullptr, 4, 6, 768, 0, stream);
        attn_mfma<<<dim3(BB * HH), 256, 0, stream>>>(qkvbuf, xnT);
        launch_gemm<1>(xnT, woT + (size_t)l * 131072, bo + l * CC,
                       x, nullptr, 4, 2, 256, 0, stream);
        ln_kernel<<<dim3(BT / 4), 256, 0, stream>>>(x, ln2g + l * CC, ln2b + l * CC, xnT);
        launch_gemm<2>(xnT, w1T + (size_t)l * 524288, b1 + l * 1024,
                       nullptr, hiddenT, 4, 8, 1024, 16, stream);
        launch_gemm<1>(hiddenT, w2T + (size_t)l * 524288, b2 + l * CC,
                       x, nullptr, 16, 2, 256, 0, stream);
    }
    ln_kernel<<<dim3(BT / 4), 256, 0, stream>>>(x, lnfg, lnfb, xnT);
    launch_gemm<3>(xnT, lmT, lmb, out, nullptr, 4, 1, VV, 0, stream);

    hipMemsetAsync(out + (size_t)BT * VV, 0, sizeof(float), stream);
    loss_kernel<<<dim3(BT / 256), 256, 0, stream>>>(out, tgt, out + (size_t)BT * VV);
}

// Round 7
// 996.888 us; speedup vs baseline: 2.8322x; 1.2123x over previous
//
#include <hip/hip_runtime.h>
#include <hip/hip_bf16.h>
#include <math.h>

#define BB 64
#define TT 256
#define CC 256
#define VV 65
#define LL 6
#define HH 8
#define BT (BB*TT)   // 16384

typedef unsigned short u16;
typedef __attribute__((ext_vector_type(8))) _Float16 h8v;   // 8 fp16 (4 VGPRs)
typedef __attribute__((ext_vector_type(4))) float f4v;      // MFMA acc
typedef __attribute__((ext_vector_type(8))) unsigned short u16x8;
typedef __attribute__((ext_vector_type(4))) unsigned short u16x4;

typedef const unsigned int __attribute__((address_space(1))) gu32;
typedef unsigned int       __attribute__((address_space(3))) lu32;

__device__ inline u16 f2h(float f) { _Float16 h = (_Float16)f; return *(u16*)&h; }

__device__ inline void gld_lds16(const void* g, void* l) {
    __builtin_amdgcn_global_load_lds((gu32*)g, (lu32*)l, 16, 0, 0);
}

// Tiled operand format: matrix [R, K] -> tiles [R/128][K/64]; tile = 16384 B
// fp16, swizzled: element (r,k) at ushort index r*64 + ((k>>3)^(r&7))*8 + (k&7).

// ---------------- pack weights: W[K][N] -> tiled B^T fp16 ----------------
__global__ __launch_bounds__(256)
void pack_std(const float* __restrict__ src, u16* __restrict__ dst,
              int K, int N, int NT, int KT, int L) {
    int id = blockIdx.x * 256 + threadIdx.x;
    int perLayer = NT * KT * 8192;
    if (id >= perLayer * L) return;
    int l = id / perLayer; int rem = id - l * perLayer;
    int tile = rem >> 13;
    int within = rem & 8191;
    int nT = tile / KT, kT = tile - nT * KT;
    int colIn = within >> 6, u = within & 63;
    int sSw = u >> 3, j = u & 7;
    int s = sSw ^ (colIn & 7);
    int k = kT * 64 + s * 8 + j;
    int n = nT * 128 + colIn;
    float v = (n < N) ? src[((size_t)l * K + k) * N + n] : 0.f;
    dst[((size_t)l * NT * KT + tile) * 8192 + within] = f2h(v);
}

// qkv weights: src wq/wk/wv [L][H][C][32] -> packed [K=256][N=768] tiled
__global__ __launch_bounds__(256)
void pack_qkv(const float* __restrict__ wq, const float* __restrict__ wk,
              const float* __restrict__ wv, u16* __restrict__ dst) {
    int id = blockIdx.x * 256 + threadIdx.x;
    const int perLayer = 24 * 8192;
    if (id >= perLayer * LL) return;
    int l = id / perLayer; int rem = id - l * perLayer;
    int tile = rem >> 13;
    int within = rem & 8191;
    int nT = tile >> 2, kT = tile & 3;
    int colIn = within >> 6, u = within & 63;
    int sSw = u >> 3, j = u & 7;
    int s = sSw ^ (colIn & 7);
    int k = kT * 64 + s * 8 + j;
    int n = nT * 128 + colIn;
    int which = n >> 8, hd = n & 255, h = hd >> 5, d = hd & 31;
    const float* src = (which == 0) ? wq : (which == 1) ? wk : wv;
    float v = src[(((size_t)l * HH + h) * CC + k) * 32 + d];
    dst[((size_t)l * 24 + tile) * 8192 + within] = f2h(v);
}

__global__ __launch_bounds__(256)
void pack_qkv_bias(const float* __restrict__ bq, const float* __restrict__ bk,
                   const float* __restrict__ bv, float* __restrict__ Bp) {
    int e = blockIdx.x * 256 + threadIdx.x;
    if (e >= LL * 768) return;
    int l = e / 768, j = e % 768;
    int which = j >> 8, hd = j & 255, h = hd >> 5, d = hd & 31;
    const float* src = (which == 0) ? bq : (which == 1) ? bk : bv;
    Bp[e] = src[((size_t)l * HH + h) * 32 + d];
}

// ---------------- embedding ----------------
__global__ __launch_bounds__(256)
void embed_kernel(const int* __restrict__ idx, const float* __restrict__ te,
                  const float* __restrict__ pe, float* __restrict__ x) {
    int i = blockIdx.x * blockDim.x + threadIdx.x;
    if (i >= BT * 64) return;
    int bt = i >> 6, c4 = i & 63;
    int tok = idx[bt];
    int t = bt & (TT - 1);
    float4 a = ((const float4*)te)[(size_t)tok * 64 + c4];
    float4 p = ((const float4*)pe)[(size_t)t * 64 + c4];
    float4 o; o.x = a.x + p.x; o.y = a.y + p.y; o.z = a.z + p.z; o.w = a.w + p.w;
    ((float4*)x)[i] = o;
}

// ---------------- layernorm -> tiled fp16 ----------------
__global__ __launch_bounds__(256)
void ln_kernel(const float* __restrict__ x, const float* __restrict__ g,
               const float* __restrict__ b, u16* __restrict__ outT) {
    int lane = threadIdx.x & 63;
    int wave = threadIdx.x >> 6;
    int row = blockIdx.x * 4 + wave;
    float4 v = ((const float4*)(x + (size_t)row * CC))[lane];
    float s = v.x + v.y + v.z + v.w;
    #pragma unroll
    for (int m = 1; m < 64; m <<= 1) s += __shfl_xor(s, m, 64);
    float mu = s * (1.f / CC);
    float dx = v.x - mu, dy = v.y - mu, dz = v.z - mu, dw = v.w - mu;
    float vs = dx * dx + dy * dy + dz * dz + dw * dw;
    #pragma unroll
    for (int m = 1; m < 64; m <<= 1) vs += __shfl_xor(vs, m, 64);
    float rs = rsqrtf(vs * (1.f / CC) + 1e-5f);
    float4 gv = ((const float4*)g)[lane];
    float4 bv = ((const float4*)b)[lane];
    float o[4];
    o[0] = dx * rs * gv.x + bv.x;
    o[1] = dy * rs * gv.y + bv.y;
    o[2] = dz * rs * gv.z + bv.z;
    o[3] = dw * rs * gv.w + bv.w;
    int rIn = row & 127, mT = row >> 7;
    int kT = lane >> 4;
    int kIn = (lane * 4) & 63;
    int slot = kIn >> 3, j = kIn & 7;          // j = 0 or 4
    size_t base = ((size_t)mT * 4 + kT) * 8192;
    int ub = rIn * 64 + ((slot ^ (rIn & 7)) << 3) + j;
    u16x4 hv;
    #pragma unroll
    for (int q = 0; q < 4; ++q) hv[q] = f2h(o[q]);
    *(u16x4*)(outT + base + ub) = hv;
}

// ---------------- MFMA GEMM: C[16384, N] = A @ W  (A,B tiled fp16) ----------
// BM=128 BN=128 BK=64, 256 thr (4 waves, 2x2), double-buffered 2-phase prefetch.
// EPI 0: fp32 + bias | 2: bias+relu -> tiled fp16 | 3: N=65 out | 4: atomicAdd(+bias@chunk0)
template<int EPI>
__global__ __launch_bounds__(256)
void gemm_mfma(const u16* __restrict__ At, const u16* __restrict__ Bt,
               const float* __restrict__ bias, float* __restrict__ Co,
               u16* __restrict__ CoT, int KTfull, int KTc, int NT, int N, int KTout) {
    __shared__ __align__(16) char lds[65536];   // 2 bufs x (A 16K + B 16K)
    int tid = threadIdx.x;
    int l = tid & 63, w = tid >> 6;
    int nwg = gridDim.x;
    int id = blockIdx.x;
    int cpx = nwg >> 3;                          // all grids are %8==0
    id = (id & 7) * cpx + (id >> 3);             // XCD-contiguous work chunks
    int mT = id / NT, nT = id - mT * NT;
    int ktBase = blockIdx.y * KTc;

    const char* Abase = (const char*)(At + ((size_t)mT * KTfull + ktBase) * 8192);
    const char* Bbase = (const char*)(Bt + ((size_t)nT * KTfull + ktBase) * 8192);
    int wm = w >> 1, wn = w & 1;

    f4v acc[4][4];
    #pragma unroll
    for (int i = 0; i < 4; ++i)
        #pragma unroll
        for (int j = 0; j < 4; ++j) acc[i][j] = (f4v)0.f;

    int lrow = l & 15, lg = l >> 4;

    // stage k-tile kt into buffer buf (per-wave quarter; linear LDS dest)
    #define STAGE(buf, kt) {                                           \
        char* la = lds + (buf) * 32768 + w * 4096;                     \
        char* lb = lds + (buf) * 32768 + 16384 + w * 4096;             \
        const char* ga = Abase + (kt) * 16384 + w * 4096 + l * 16;     \
        const char* gb = Bbase + (kt) * 16384 + w * 4096 + l * 16;     \
        _Pragma("unroll")                                              \
        for (int j = 0; j < 4; ++j) {                                  \
            gld_lds16(ga + j * 1024, la + j * 1024);                   \
            gld_lds16(gb + j * 1024, lb + j * 1024);                   \
        } }

    STAGE(0, 0);
    __syncthreads();
    int cur = 0;
    for (int kt = 0; kt < KTc; ++kt) {
        if (kt + 1 < KTc) STAGE(cur ^ 1, kt + 1);   // prefetch overlaps compute
        const char* lb0 = lds + cur * 32768;
        #pragma unroll
        for (int kh = 0; kh < 2; ++kh) {
            h8v ah[4], bh[4];
            #pragma unroll
            for (int mi = 0; mi < 4; ++mi) {
                int rc = wm * 64 + mi * 16 + lrow;
                ah[mi] = *(const h8v*)(lb0 + rc * 128 + 16 * ((kh * 4 + lg) ^ (rc & 7)));
            }
            #pragma unroll
            for (int ni = 0; ni < 4; ++ni) {
                int rc = wn * 64 + ni * 16 + lrow;
                bh[ni] = *(const h8v*)(lb0 + 16384 + rc * 128 + 16 * ((kh * 4 + lg) ^ (rc & 7)));
            }
            #pragma unroll
            for (int mi = 0; mi < 4; ++mi)
                #pragma unroll
                for (int ni = 0; ni < 4; ++ni)
                    acc[mi][ni] = __builtin_amdgcn_mfma_f32_16x16x32_f16(ah[mi], bh[ni], acc[mi][ni], 0, 0, 0);
        }
        __syncthreads();
        cur ^= 1;
    }
    #undef STAGE

    // epilogue: C frag layout col = l&15, row = (l>>4)*4 + q  [m89-verified]
    int colbase = nT * 128 + wn * 64;
    if (EPI == 0) {
        #pragma unroll
        for (int mi = 0; mi < 4; ++mi) {
            int r0 = mT * 128 + wm * 64 + mi * 16 + lg * 4;
            #pragma unroll
            for (int ni = 0; ni < 4; ++ni) {
                int cg = colbase + ni * 16 + lrow;
                float bv = bias[cg];
                #pragma unroll
                for (int q = 0; q < 4; ++q)
                    Co[(size_t)(r0 + q) * N + cg] = acc[mi][ni][q] + bv;
            }
        }
    } else if (EPI == 2) {
        #pragma unroll
        for (int mi = 0; mi < 4; ++mi) {
            int rr = wm * 64 + mi * 16 + lg * 4;
            #pragma unroll
            for (int ni = 0; ni < 4; ++ni) {
                int cg = colbase + ni * 16 + lrow;
                float bv = bias[cg];
                int kTo = cg >> 6, kIn = cg & 63;
                size_t tbase = ((size_t)mT * KTout + kTo) * 8192;
                #pragma unroll
                for (int q = 0; q < 4; ++q) {
                    int rIn = rr + q;
                    float f = fmaxf(acc[mi][ni][q] + bv, 0.f);
                    int ub = rIn * 64 + (((kIn >> 3) ^ (rIn & 7)) << 3) + (kIn & 7);
                    CoT[tbase + ub] = f2h(f);
                }
            }
        }
    } else if (EPI == 3) {  // lm head, N=65 bounds
        #pragma unroll
        for (int mi = 0; mi < 4; ++mi) {
            int r0 = mT * 128 + wm * 64 + mi * 16 + lg * 4;
            #pragma unroll
            for (int ni = 0; ni < 4; ++ni) {
                int cg = colbase + ni * 16 + lrow;
                if (cg < VV) {
                    float bv = bias[cg];
                    #pragma unroll
                    for (int q = 0; q < 4; ++q)
                        Co[(size_t)(r0 + q) * VV + cg] = acc[mi][ni][q] + bv;
                }
            }
        }
    } else {  // EPI 4: split-K atomic accumulate into residual buffer
        #pragma unroll
        for (int mi = 0; mi < 4; ++mi) {
            int r0 = mT * 128 + wm * 64 + mi * 16 + lg * 4;
            #pragma unroll
            for (int ni = 0; ni < 4; ++ni) {
                int cg = colbase + ni * 16 + lrow;
                float bv = (ktBase == 0) ? bias[cg] : 0.f;
                #pragma unroll
                for (int q = 0; q < 4; ++q)
                    atomicAdd(Co + (size_t)(r0 + q) * N + cg, acc[mi][ni][q] + bv);
            }
        }
    }
}

// ---------------- MFMA flash attention: block per (b,h), 4 waves ----------------
// LDS: K fp16 [256 rows][80B] @0 ; V^T fp16 [32 rows][528B] @20480 ;
//      P per wave [16 rows][80B] @37376 + w*1280.  Total 42496 B.
// Wave w owns m-tiles {w, 7-w, 8+w, 15-w} (balanced causal work).
__global__ __launch_bounds__(256)
void attn_mfma(const float* __restrict__ qkv, u16* __restrict__ outT) {
    __shared__ __align__(16) char lds[42496];
    int bh = blockIdx.x;
    bh = (bh & 7) * 64 + (bh >> 3);      // bijective XCD swizzle (512 = 8*64)
    int b = bh >> 3, h = bh & 7;
    const float* base = qkv + (size_t)b * TT * 768;
    int tid = threadIdx.x;
    int w = tid >> 6, l = tid & 63;
    int li = l & 15, g = l >> 4;

    // ---- stage K (row-major) and V^T ----
    {
        int r0 = tid >> 3, c = tid & 7;
        #pragma unroll
        for (int it = 0; it < 8; ++it) {
            int t = it * 32 + r0;
            float4 kv = *(const float4*)(base + (size_t)t * 768 + 256 + h * 32 + c * 4);
            float4 vv = *(const float4*)(base + (size_t)t * 768 + 512 + h * 32 + c * 4);
            u16x4 kh;
            kh[0] = f2h(kv.x); kh[1] = f2h(kv.y); kh[2] = f2h(kv.z); kh[3] = f2h(kv.w);
            *(u16x4*)(lds + t * 80 + c * 8) = kh;
            *(u16*)(lds + 20480 + (c * 4 + 0) * 528 + t * 2) = f2h(vv.x);
            *(u16*)(lds + 20480 + (c * 4 + 1) * 528 + t * 2) = f2h(vv.y);
            *(u16*)(lds + 20480 + (c * 4 + 2) * 528 + t * 2) = f2h(vv.z);
            *(u16*)(lds + 20480 + (c * 4 + 3) * 528 + t * 2) = f2h(vv.w);
        }
    }
    __syncthreads();

    char* Pb = lds + 37376 + w * 1280;
    int mts[4] = {w, 7 - w, 8 + w, 15 - w};
    #pragma unroll
    for (int im = 0; im < 4; ++im) {
        int mt = mts[im];
        int mq = mt * 16;
        const float* qp = base + (size_t)(mq + li) * 768 + h * 32 + g * 8;
        float4 q0 = *(const float4*)qp;
        float4 q1 = *(const float4*)(qp + 4);
        h8v aq;
        aq[0] = (_Float16)q0.x; aq[1] = (_Float16)q0.y;
        aq[2] = (_Float16)q0.z; aq[3] = (_Float16)q0.w;
        aq[4] = (_Float16)q1.x; aq[5] = (_Float16)q1.y;
        aq[6] = (_Float16)q1.z; aq[7] = (_Float16)q1.w;

        f4v o0 = (f4v)0.f, o1 = (f4v)0.f;
        float mrun0 = -1e30f, mrun1 = -1e30f, mrun2 = -1e30f, mrun3 = -1e30f;
        float lrun0 = 0.f, lrun1 = 0.f, lrun2 = 0.f, lrun3 = 0.f;
        int nu = (mt >> 1) + 1;
        for (int kt = 0; kt < nu; ++kt) {
            int kb = kt * 32;
            h8v kf0 = *(const h8v*)(lds + (kb + li) * 80 + g * 16);
            h8v kf1 = *(const h8v*)(lds + (kb + 16 + li) * 80 + g * 16);
            f4v s0 = __builtin_amdgcn_mfma_f32_16x16x32_f16(aq, kf0, (f4v)0.f, 0, 0, 0);
            f4v s1 = __builtin_amdgcn_mfma_f32_16x16x32_f16(aq, kf1, (f4v)0.f, 0, 0, 0);
            bool maskunit = (kt == nu - 1);
            float p0[4], p1[4];
            float* mr[4] = {&mrun0, &mrun1, &mrun2, &mrun3};
            float* lr[4] = {&lrun0, &lrun1, &lrun2, &lrun3};
            #pragma unroll
            for (int qq = 0; qq < 4; ++qq) {
                float v0 = s0[qq] * 0.0625f;     // scale = C^-0.5 = 1/16
                float v1 = s1[qq] * 0.0625f;
                if (maskunit) {
                    int qg = mq + g * 4 + qq;
                    if (kb + li > qg)      v0 = -1e30f;
                    if (kb + 16 + li > qg) v1 = -1e30f;
                }
                float tm = fmaxf(v0, v1);
                #pragma unroll
                for (int msk = 1; msk < 16; msk <<= 1)
                    tm = fmaxf(tm, __shfl_xor(tm, msk, 64));
                float mold = *mr[qq];
                float mnew = fmaxf(mold, tm);
                float corr = __expf(mold - mnew);
                float e0 = __expf(v0 - mnew);
                float e1 = __expf(v1 - mnew);
                float ts = e0 + e1;
                #pragma unroll
                for (int msk = 1; msk < 16; msk <<= 1)
                    ts += __shfl_xor(ts, msk, 64);
                *lr[qq] = *lr[qq] * corr + ts;
                *mr[qq] = mnew;
                o0[qq] *= corr; o1[qq] *= corr;
                p0[qq] = e0; p1[qq] = e1;
            }
            #pragma unroll
            for (int qq = 0; qq < 4; ++qq) {
                *(u16*)(Pb + (g * 4 + qq) * 80 + li * 2)        = f2h(p0[qq]);
                *(u16*)(Pb + (g * 4 + qq) * 80 + (16 + li) * 2) = f2h(p1[qq]);
            }
            h8v pf  = *(const h8v*)(Pb + li * 80 + g * 16);
            h8v vf0 = *(const h8v*)(lds + 20480 + li * 528        + kb * 2 + g * 16);
            h8v vf1 = *(const h8v*)(lds + 20480 + (16 + li) * 528 + kb * 2 + g * 16);
            o0 = __builtin_amdgcn_mfma_f32_16x16x32_f16(pf, vf0, o0, 0, 0, 0);
            o1 = __builtin_amdgcn_mfma_f32_16x16x32_f16(pf, vf1, o1, 0, 0, 0);
        }
        float invs[4] = {1.f / lrun0, 1.f / lrun1, 1.f / lrun2, 1.f / lrun3};
        #pragma unroll
        for (int qq = 0; qq < 4; ++qq) {
            int tok = mq + g * 4 + qq;
            int rIn = tok & 127;
            size_t tb = ((size_t)(b * 2 + (tok >> 7)) * 4 + (h >> 1)) * 8192;
            float f0 = o0[qq] * invs[qq];
            float f1 = o1[qq] * invs[qq];
            int kIn0 = (h & 1) * 32 + li;
            int kIn1 = kIn0 + 16;
            int ub0 = rIn * 64 + (((kIn0 >> 3) ^ (rIn & 7)) << 3) + (kIn0 & 7);
            int ub1 = rIn * 64 + (((kIn1 >> 3) ^ (rIn & 7)) << 3) + (kIn1 & 7);
            outT[tb + ub0] = f2h(f0);
            outT[tb + ub1] = f2h(f1);
        }
    }
}

// ---------------- loss ----------------
__global__ __launch_bounds__(256)
void loss_kernel(const float* __restrict__ lg, const int* __restrict__ tgt,
                 float* __restrict__ loss) {
    int row = blockIdx.x * 256 + threadIdx.x;
    const float* r = lg + (size_t)row * VV;
    float mx = -INFINITY;
    for (int v = 0; v < VV; ++v) mx = fmaxf(mx, r[v]);
    float se = 0.f;
    for (int v = 0; v < VV; ++v) se += __expf(r[v] - mx);
    float nl = mx + __logf(se) - r[tgt[row]];
    #pragma unroll
    for (int m = 1; m < 64; m <<= 1) nl += __shfl_xor(nl, m, 64);
    __shared__ float wsum[4];
    int lane = threadIdx.x & 63, wv = threadIdx.x >> 6;
    if (lane == 0) wsum[wv] = nl;
    __syncthreads();
    if (threadIdx.x == 0)
        atomicAdd(loss, (wsum[0] + wsum[1] + wsum[2] + wsum[3]) * (1.f / BT));
}

// ---------------- host-side dispatch ----------------
template<int EPI>
static void launch_gemm(const u16* At, const u16* Bt, const float* bias,
                        float* Co, u16* CoT, int KTfull, int KTc, int splitY,
                        int NT, int N, int KTout, hipStream_t s) {
    gemm_mfma<EPI><<<dim3(128 * NT, splitY), 256, 0, s>>>(At, Bt, bias, Co, CoT,
                                                          KTfull, KTc, NT, N, KTout);
}

extern "C" void kernel_launch(void* const* d_in, const int* in_sizes, int n_in,
                              void* d_out, int out_size, void* d_ws, size_t ws_size,
                              hipStream_t stream) {
    const int*   idx  = (const int*)d_in[0];
    const int*   tgt  = (const int*)d_in[1];
    const float* te   = (const float*)d_in[2];
    const float* pe   = (const float*)d_in[3];
    const float* wq   = (const float*)d_in[4];
    const float* bq   = (const float*)d_in[5];
    const float* wk   = (const float*)d_in[6];
    const float* bk   = (const float*)d_in[7];
    const float* wv   = (const float*)d_in[8];
    const float* bv   = (const float*)d_in[9];
    const float* wo   = (const float*)d_in[10];
    const float* bo   = (const float*)d_in[11];
    const float* ln1g = (const float*)d_in[12];
    const float* ln1b = (const float*)d_in[13];
    const float* w1   = (const float*)d_in[14];
    const float* b1   = (const float*)d_in[15];
    const float* w2   = (const float*)d_in[16];
    const float* b2   = (const float*)d_in[17];
    const float* ln2g = (const float*)d_in[18];
    const float* ln2b = (const float*)d_in[19];
    const float* lnfg = (const float*)d_in[20];
    const float* lnfb = (const float*)d_in[21];
    const float* lmw  = (const float*)d_in[22];
    const float* lmb  = (const float*)d_in[23];
    float* out = (float*)d_out;

    // workspace layout (bytes)
    char* base = (char*)d_ws;
    float* x       = (float*)(base);                       // 16 MB fp32
    float* qkvbuf  = (float*)(base + (16ll << 20));        // 48 MB fp32 (shared)
    u16*   hiddenT = (u16*)  (base + (16ll << 20));        // 32 MB fp16 tiled
    u16*   xnT     = (u16*)  (base + (64ll << 20));        // 8 MB fp16 tiled
    u16*   qkvT    = (u16*)  (base + (72ll << 20));        // 2.25 MB
    u16*   woT     = (u16*)  (base + (75ll << 20));        // 0.75 MB
    u16*   w1T     = (u16*)  (base + (76ll << 20));        // 3 MB
    u16*   w2T     = (u16*)  (base + (79ll << 20));        // 3 MB
    u16*   lmT     = (u16*)  (base + (82ll << 20));        // 64 KB
    float* Bp      = (float*)(base + (83ll << 20));        // 18 KB

    // pack weights (per-launch; weights restored by harness each call)
    pack_qkv<<<dim3((LL * 24 * 8192) / 256), 256, 0, stream>>>(wq, wk, wv, qkvT);
    pack_std<<<dim3((LL * 8 * 8192) / 256), 256, 0, stream>>>(wo, woT, 256, 256, 2, 4, LL);
    pack_std<<<dim3((LL * 32 * 8192) / 256), 256, 0, stream>>>(w1, w1T, 256, 1024, 8, 4, LL);
    pack_std<<<dim3((LL * 32 * 8192) / 256), 256, 0, stream>>>(w2, w2T, 1024, 256, 2, 16, LL);
    pack_std<<<dim3((4 * 8192) / 256), 256, 0, stream>>>(lmw, lmT, 256, VV, 1, 4, 1);
    pack_qkv_bias<<<dim3((LL * 768 + 255) / 256), 256, 0, stream>>>(bq, bk, bv, Bp);

    embed_kernel<<<dim3((BT * 64) / 256), 256, 0, stream>>>(idx, te, pe, x);

    for (int l = 0; l < LL; ++l) {
        ln_kernel<<<dim3(BT / 4), 256, 0, stream>>>(x, ln1g + l * CC, ln1b + l * CC, xnT);
        launch_gemm<0>(xnT, qkvT + (size_t)l * 196608, Bp + l * 768,
                       qkvbuf, nullptr, 4, 4, 1, 6, 768, 0, stream);
        attn_mfma<<<dim3(BB * HH), 256, 0, stream>>>(qkvbuf, xnT);
        launch_gemm<4>(xnT, woT + (size_t)l * 65536, bo + l * CC,
                       x, nullptr, 4, 2, 2, 2, 256, 0, stream);
        ln_kernel<<<dim3(BT / 4), 256, 0, stream>>>(x, ln2g + l * CC, ln2b + l * CC, xnT);
        launch_gemm<2>(xnT, w1T + (size_t)l * 262144, b1 + l * 1024,
                       nullptr, hiddenT, 4, 4, 1, 8, 1024, 16, stream);
        launch_gemm<4>(hiddenT, w2T + (size_t)l * 262144, b2 + l * CC,
                       x, nullptr, 16, 8, 2, 2, 256, 0, stream);
    }
    ln_kernel<<<dim3(BT / 4), 256, 0, stream>>>(x, lnfg, lnfb, xnT);
    launch_gemm<3>(xnT, lmT, lmb, out, nullptr, 4, 4, 1, 1, VV, 0, stream);

    hipMemsetAsync(out + (size_t)BT * VV, 0, sizeof(float), stream);
    loss_kernel<<<dim3(BT / 256), 256, 0, stream>>>(out, tgt, out + (size_t)BT * VV);
}